// Round 1
// baseline (230.065 us; speedup 1.0000x reference)
//
#include <hip/hip_runtime.h>

#define N_BINS 85

// Zero the 85-float partial-sum buffer in d_ws. Runs every kernel_launch so
// the atomic accumulation is deterministic per call (no cross-call state).
__global__ void emd_zero_ws(float* __restrict__ ws) {
    int i = threadIdx.x;
    if (i < N_BINS) ws[i] = 0.0f;
}

// Grid-stride float4 pass over the flat [B*85] arrays. Accumulate per-column
// sums of (input - target) into an LDS histogram, then one global atomicAdd
// per bin per block. 42,500,000 elements is exactly divisible by 4 -> no tail.
__global__ __launch_bounds__(256) void emd_colsum_diff(
        const float* __restrict__ in, const float* __restrict__ tg,
        float* __restrict__ ws, unsigned int n4) {
    __shared__ float bins[N_BINS];
    for (int i = threadIdx.x; i < N_BINS; i += blockDim.x) bins[i] = 0.0f;
    __syncthreads();

    const float4* __restrict__ in4 = (const float4*)in;
    const float4* __restrict__ tg4 = (const float4*)tg;
    unsigned int stride = gridDim.x * blockDim.x;

    for (unsigned int i = blockIdx.x * blockDim.x + threadIdx.x; i < n4; i += stride) {
        float4 a = in4[i];
        float4 b = tg4[i];
        // flat element index of a.x is 4*i; column = (4*i) % 85
        unsigned int c = (4u * i) % N_BINS;
        atomicAdd(&bins[c], a.x - b.x);
        c = (c + 1 == N_BINS) ? 0 : c + 1;
        atomicAdd(&bins[c], a.y - b.y);
        c = (c + 1 == N_BINS) ? 0 : c + 1;
        atomicAdd(&bins[c], a.z - b.z);
        c = (c + 1 == N_BINS) ? 0 : c + 1;
        atomicAdd(&bins[c], a.w - b.w);
    }
    __syncthreads();

    for (int i = threadIdx.x; i < N_BINS; i += blockDim.x) {
        atomicAdd(&ws[i], bins[i]);
    }
}

// O(85) epilogue: d_j = |ws_j|; c = cumsum(d); loss = sum(c[m-1]/m) / 10.
__global__ void emd_finalize(const float* __restrict__ ws, float* __restrict__ out) {
    if (threadIdx.x == 0 && blockIdx.x == 0) {
        float c = 0.0f;
        float loss = 0.0f;
        for (int m = 1; m <= N_BINS; ++m) {
            c += fabsf(ws[m - 1]);
            loss += c / (float)m;
        }
        out[0] = loss * 0.1f;
    }
}

extern "C" void kernel_launch(void* const* d_in, const int* in_sizes, int n_in,
                              void* d_out, int out_size, void* d_ws, size_t ws_size,
                              hipStream_t stream) {
    const float* in = (const float*)d_in[0];
    const float* tg = (const float*)d_in[1];
    float* out = (float*)d_out;
    float* ws  = (float*)d_ws;

    unsigned int n  = (unsigned int)in_sizes[0];      // 500000 * 85 = 42,500,000
    unsigned int n4 = n / 4u;                          // exactly divisible

    emd_zero_ws<<<1, 128, 0, stream>>>(ws);

    const int block = 256;
    unsigned int want = (n4 + block - 1) / block;
    unsigned int grid = want < 2048u ? want : 2048u;   // grid-stride cap per G11
    emd_colsum_diff<<<grid, block, 0, stream>>>(in, tg, ws, n4);

    emd_finalize<<<1, 64, 0, stream>>>(ws, out);
}

// Round 2
// 87.154 us; speedup vs baseline: 2.6397x; 2.6397x over previous
//
#include <hip/hip_runtime.h>

#define N_BINS 85

// Zero the 85-float accumulator in d_ws each call (deterministic per launch).
__global__ void emd_zero_ws(float* __restrict__ ws) {
    int i = threadIdx.x;
    if (i < N_BINS) ws[i] = 0.0f;
}

// Key invariant: grid*block (in float4 units) is a multiple of 85, so each
// thread's flat element index mod 85 is CONSTANT across grid-stride iters.
// -> per-thread register accumulation of its 4 fixed columns, zero atomics
// in the inner loop. 1020 blocks * 256 thr = 261,120 = 85 * 3072.
__global__ __launch_bounds__(256) void emd_colsum(
        const float* __restrict__ in, const float* __restrict__ tg,
        float* __restrict__ ws, unsigned int n4) {
    const float4* __restrict__ in4 = (const float4*)in;
    const float4* __restrict__ tg4 = (const float4*)tg;

    unsigned int t      = blockIdx.x * blockDim.x + threadIdx.x;
    unsigned int stride = gridDim.x * blockDim.x;   // multiple of 85

    float s0 = 0.0f, s1 = 0.0f, s2 = 0.0f, s3 = 0.0f;

    #pragma unroll 4
    for (unsigned int i = t; i < n4; i += stride) {
        float4 a = in4[i];
        float4 b = tg4[i];
        s0 += a.x - b.x;
        s1 += a.y - b.y;
        s2 += a.z - b.z;
        s3 += a.w - b.w;
    }

    // Columns for this thread (fixed): (4t, 4t+1, 4t+2, 4t+3) mod 85
    unsigned int c0 = (4u * t) % N_BINS;
    unsigned int c1 = (c0 + 1u == N_BINS) ? 0u : c0 + 1u;
    unsigned int c2 = (c1 + 1u == N_BINS) ? 0u : c1 + 1u;
    unsigned int c3 = (c2 + 1u == N_BINS) ? 0u : c2 + 1u;

    __shared__ float bins[N_BINS];
    for (int i = threadIdx.x; i < N_BINS; i += blockDim.x) bins[i] = 0.0f;
    __syncthreads();

    // One-time epilogue: 4 LDS atomics per thread (1024 adds over 85 bins).
    atomicAdd(&bins[c0], s0);
    atomicAdd(&bins[c1], s1);
    atomicAdd(&bins[c2], s2);
    atomicAdd(&bins[c3], s3);
    __syncthreads();

    // 85 global atomics per block; 1020 adds per address total.
    for (int i = threadIdx.x; i < N_BINS; i += blockDim.x) {
        atomicAdd(&ws[i], bins[i]);
    }
}

// O(85) epilogue: d_j = |ws_j|; c = cumsum(d); loss = sum(c[m-1]/m) / 10.
__global__ void emd_finalize(const float* __restrict__ ws, float* __restrict__ out) {
    if (threadIdx.x == 0 && blockIdx.x == 0) {
        float c = 0.0f;
        float loss = 0.0f;
        for (int m = 1; m <= N_BINS; ++m) {
            c += fabsf(ws[m - 1]);
            loss += c / (float)m;
        }
        out[0] = loss * 0.1f;
    }
}

extern "C" void kernel_launch(void* const* d_in, const int* in_sizes, int n_in,
                              void* d_out, int out_size, void* d_ws, size_t ws_size,
                              hipStream_t stream) {
    const float* in = (const float*)d_in[0];
    const float* tg = (const float*)d_in[1];
    float* out = (float*)d_out;
    float* ws  = (float*)d_ws;

    unsigned int n  = (unsigned int)in_sizes[0];   // 42,500,000
    unsigned int n4 = n / 4u;                      // 10,625,000 (exact)

    emd_zero_ws<<<1, 128, 0, stream>>>(ws);

    // 1020 = 12*85 blocks; 1020*256 = 85*3072 keeps per-thread columns fixed.
    emd_colsum<<<1020, 256, 0, stream>>>(in, tg, ws, n4);

    emd_finalize<<<1, 64, 0, stream>>>(ws, out);
}